// Round 13
// baseline (423.969 us; speedup 1.0000x reference)
//
#include <hip/hip_runtime.h>

#define BN_EPS 1e-5f

typedef __bf16 bf16x8 __attribute__((ext_vector_type(8)));
typedef float f32x4 __attribute__((ext_vector_type(4)));
typedef unsigned int uint;
typedef unsigned short ushort;
typedef unsigned char uchar;

__device__ __forceinline__ ushort f2bf(float f) {
  union { float f; uint u; } v; v.f = f;
  uint r = v.u + 0x7FFF + ((v.u >> 16) & 1);   // RNE
  return (ushort)(r >> 16);
}
__device__ __forceinline__ float bf2f_lo(uint u) {
  union { uint i; float f; } v; v.i = u << 16; return v.f;
}
__device__ __forceinline__ float bf2f_hi(uint u) {
  union { uint i; float f; } v; v.i = u & 0xffff0000u; return v.f;
}
__device__ __forceinline__ uint pack2(float a, float b) {
  return (uint)f2bf(a) | ((uint)f2bf(b) << 16);
}

// ---- fp8 e4m3 (non-negative h only; h >= 0 holds inductively: ReLU + residual) ----
__device__ __forceinline__ uint f2e4m3(float f) {
  union { float f; uint u; } v; v.f = f * 0x1p-120f;
  uint r = v.u + 0x7FFFF + ((v.u >> 20) & 1);
  uint u8 = r >> 20;
  return u8 > 0x7Eu ? 0x7Eu : u8;
}
__device__ __forceinline__ float e4m32f(uint u8) {
  union { uint u; float f; } v; v.u = (u8 & 0x7Fu) << 20;
  return v.f * 0x1p120f;
}

// ---------------- zero counters + weight prep (one kernel) ----------------
// Blocks < NB2 zero cnt|cur|cursor; blocks >= NB2 build split-K frag-major
// bf16 weights. Completes fully before gemm_in_hist (stream-serial).

__global__ void zero_prep_kernel(int* __restrict__ zreg, int NZ,
                                 const float* __restrict__ W_in, const float* __restrict__ Wl,
                                 const float* __restrict__ Wr, ushort* __restrict__ Bfm,
                                 int NB2) {
  int b = blockIdx.x;
  if (b < NB2) {
    int i = b * 256 + threadIdx.x;
    if (i < NZ) zreg[i] = 0;
    return;
  }
  int p = (b - NB2) * 256 + threadIdx.x;
  int mat = p >> 12;
  int rem = p & 4095;
  int half = rem >> 11;
  int rem2 = rem & 2047;
  int nt = rem2 >> 8, kt2 = (rem2 >> 6) & 3, lane = rem2 & 63;
  int n = nt * 16 + (lane & 15);
  int k0 = (half * 4 + kt2) * 32 + (lane >> 4) * 8;
  ushort tmp[8];
  #pragma unroll
  for (int j = 0; j < 8; ++j) {
    int k = k0 + j;
    float v;
    if (mat == 0) v = W_in[k * 128 + n];
    else {
      int l = mat - 1;
      v = (k < 128) ? Wl[l * 16384 + k * 128 + n] : Wr[l * 16384 + (k - 128) * 128 + n];
    }
    tmp[j] = f2bf(v);
  }
  *(uint4*)&Bfm[(size_t)p * 8] = *(const uint4*)tmp;
}

// ---------------- CSR build (bump allocation) ----------------

__global__ void reserve_kernel(const int* __restrict__ cnt, int* __restrict__ rowbeg,
                               int* __restrict__ cursor, int N) {
  int tid = threadIdx.x;
  int i = blockIdx.x * 256 + tid;
  int v = (i < N) ? cnt[i] : 0;
  int lane = tid & 63;
  int x = v;
  #pragma unroll
  for (int off = 1; off < 64; off <<= 1) {
    int y = __shfl_up(x, off, 64);
    if (lane >= off) x += y;
  }
  int ret = 0;
  if (lane == 63) ret = atomicAdd(cursor, x);
  int base = __shfl(ret, 63);
  if (i < N) rowbeg[i] = base + x - v;
}

__global__ void fill_kernel(const int* __restrict__ src, const int* __restrict__ dst,
                            const int* __restrict__ rowbeg, int* __restrict__ cur,
                            int* __restrict__ col, int E) {
  int e = blockIdx.x * 256 + threadIdx.x;
  if (e < E) {
    int d = dst[e];
    int p = rowbeg[d] + atomicAdd(&cur[d], 1);
    col[p] = src[e];
  }
}

// ---------------- mean aggregation: fp8 gather, quarter-wave per node -----

__global__ void agg_kernel(const int* __restrict__ rowbeg, const int* __restrict__ deg,
                           const int* __restrict__ col,
                           const uchar* __restrict__ h8, ushort* __restrict__ agg, int N) {
  int node = blockIdx.x * 16 + (threadIdx.x >> 4);
  if (node >= N) return;
  int lane = threadIdx.x & 15;
  const uchar* hp = h8 + lane * 8;
  int beg = rowbeg[node];
  int d = deg[node];
  float di = 1.0f / (float)(d > 0 ? d : 1);
  int end = beg + d;
  float a0 = 0.f, a1 = 0.f, a2 = 0.f, a3 = 0.f;
  float a4 = 0.f, a5 = 0.f, a6 = 0.f, a7 = 0.f;
  #pragma unroll 1
  for (int e = beg; e < end; e += 8) {
    int cc[8];
    #pragma unroll
    for (int j = 0; j < 8; ++j) {
      int idx = e + j;
      cc[j] = col[idx < end ? idx : e];
    }
    uint2 v[8];
    #pragma unroll
    for (int j = 0; j < 8; ++j)
      v[j] = *(const uint2*)(hp + (size_t)cc[j] * 128);
    #pragma unroll
    for (int j = 1; j < 8; ++j)
      if (e + j >= end) { v[j].x = 0u; v[j].y = 0u; }
    #pragma unroll
    for (int j = 0; j < 8; ++j) {
      a0 += e4m32f(v[j].x);        a1 += e4m32f(v[j].x >> 8);
      a2 += e4m32f(v[j].x >> 16);  a3 += e4m32f(v[j].x >> 24);
      a4 += e4m32f(v[j].y);        a5 += e4m32f(v[j].y >> 8);
      a6 += e4m32f(v[j].y >> 16);  a7 += e4m32f(v[j].y >> 24);
    }
  }
  uint4 o;
  o.x = pack2(a0 * di, a1 * di);
  o.y = pack2(a2 * di, a3 * di);
  o.z = pack2(a4 * di, a5 * di);
  o.w = pack2(a6 * di, a7 * di);
  *(uint4*)(agg + (size_t)node * 128 + lane * 8) = o;
}

// ---------------- MFMA GEMM (layers): BM=64, in-place over A0, depth-2 A ------
// out ALIASES A0 (in-place; __syncthreads() fences reads before stores).
// A depth-2 (3-slot a_buf): small win (~-2us/layer, R12 back-solve). B depth-1.

template<bool F32OUT>
__global__ __launch_bounds__(256, 4)
void gemm_layer(const ushort* A0, const ushort* __restrict__ A1,
                const ushort* __restrict__ Bfm, const float* __restrict__ bias,
                const float* __restrict__ gamma, const float* __restrict__ beta,
                const float* __restrict__ mean, const float* __restrict__ var,
                const ushort* residual, void* out,
                uchar* __restrict__ out8, int N) {
  __shared__ float Cb_all[4 * 16 * 68];
  int tid = threadIdx.x, wave = tid >> 6, lane = tid & 63;
  int wm = wave >> 1, wn = wave & 1, quad = lane >> 4, l16 = lane & 15;
  int m0 = blockIdx.x * 64;

  int rowm[2];
  #pragma unroll
  for (int mt = 0; mt < 2; ++mt) {
    int r = m0 + wm * 32 + mt * 16 + l16;
    rowm[mt] = r < N ? r : N - 1;
  }

  uint4 a_buf[3][2], b_buf[2][4];
  #pragma unroll
  for (int mt = 0; mt < 2; ++mt) {
    a_buf[0][mt] = *(const uint4*)(A0 + (size_t)rowm[mt] * 128 + quad * 8);
    a_buf[1][mt] = *(const uint4*)(A0 + (size_t)rowm[mt] * 128 + 32 + quad * 8);
  }
  {
    const ushort* bp = Bfm + (size_t)(wn * 4 * 256 + lane) * 8;
    #pragma unroll
    for (int nt = 0; nt < 4; ++nt)
      b_buf[0][nt] = *(const uint4*)(bp + nt * 2048);
  }

  f32x4 acc[2][4] = {};

  #pragma unroll
  for (int kt = 0; kt < 8; ++kt) {
    if (kt < 6) {
      int k2 = kt + 2;
      const ushort* bse = (k2 < 4) ? A0 : A1;
      int ko = (k2 & 3) * 32 + quad * 8;
      #pragma unroll
      for (int mt = 0; mt < 2; ++mt)
        a_buf[k2 % 3][mt] = *(const uint4*)(bse + (size_t)rowm[mt] * 128 + ko);
    }
    if (kt < 7) {
      int k1 = kt + 1;
      const ushort* bp = Bfm + ((size_t)(k1 >> 2) * 16384 +
                                (size_t)((wn * 4) * 256 + (k1 & 3) * 64 + lane) * 8);
      #pragma unroll
      for (int nt = 0; nt < 4; ++nt)
        b_buf[k1 & 1][nt] = *(const uint4*)(bp + nt * 2048);
    }
    __builtin_amdgcn_sched_barrier(0);   // loads stay issued ahead of the MFMAs
    #pragma unroll
    for (int mt = 0; mt < 2; ++mt) {
      bf16x8 af = __builtin_bit_cast(bf16x8, a_buf[kt % 3][mt]);
      #pragma unroll
      for (int nt = 0; nt < 4; ++nt)
        acc[mt][nt] = __builtin_amdgcn_mfma_f32_16x16x32_bf16(
            af, __builtin_bit_cast(bf16x8, b_buf[kt & 1][nt]), acc[mt][nt], 0, 0, 0);
    }
  }

  // bias + BN + ReLU in registers
  #pragma unroll
  for (int nt = 0; nt < 4; ++nt) {
    int c = wn * 64 + nt * 16 + l16;
    float sc = gamma[c] * rsqrtf(var[c] + BN_EPS);
    float sh = beta[c] - mean[c] * sc;
    float bi = bias[c];
    #pragma unroll
    for (int mt = 0; mt < 2; ++mt)
      #pragma unroll
      for (int r = 0; r < 4; ++r)
        acc[mt][nt][r] = fmaxf((acc[mt][nt][r] + bi) * sc + sh, 0.f);
  }

  // fence: all waves' A0 reads complete before any wave overwrites those rows
  __syncthreads();

  // per-wave LDS bounce for vectorized residual+store
  float* Cb = Cb_all + wave * (16 * 68);
  #pragma unroll
  for (int mt = 0; mt < 2; ++mt) {
    #pragma unroll
    for (int nt = 0; nt < 4; ++nt)
      #pragma unroll
      for (int r = 0; r < 4; ++r)
        Cb[(quad * 4 + r) * 68 + nt * 16 + l16] = acc[mt][nt][r];
    #pragma unroll
    for (int i = 0; i < 4; ++i) {
      int idx = i * 64 + lane, rowl = idx >> 4, seg = idx & 15;
      int grow = m0 + wm * 32 + mt * 16 + rowl;
      if (grow < N) {
        float4 vv = *(float4*)&Cb[rowl * 68 + seg * 4];
        uint2 rv = *(const uint2*)(residual + (size_t)grow * 128 + wn * 64 + seg * 4);
        vv.x += bf2f_lo(rv.x); vv.y += bf2f_hi(rv.x);
        vv.z += bf2f_lo(rv.y); vv.w += bf2f_hi(rv.y);
        if (F32OUT) {
          *(float4*)((float*)out + (size_t)grow * 128 + wn * 64 + seg * 4) = vv;
        } else {
          uint2 o;
          o.x = pack2(vv.x, vv.y); o.y = pack2(vv.z, vv.w);
          *(uint2*)((ushort*)out + (size_t)grow * 128 + wn * 64 + seg * 4) = o;
          uint u8 = f2e4m3(vv.x) | (f2e4m3(vv.y) << 8) |
                    (f2e4m3(vv.z) << 16) | (f2e4m3(vv.w) << 24);
          *(uint*)(out8 + (size_t)grow * 128 + wn * 64 + seg * 4) = u8;
        }
      }
    }
  }
}

// ---------------- MFMA GEMM (input proj, depth-1 X) UNION edge histogram ------
// X path REVERTED to round-11 depth-1: depth-2 on the fp32 X stream REGRESSED
// (R12: 72 -> 79 us; 3-slot addressing overhead > overlap gain — the X k-loop
// is overlap-saturated at depth-1).

__global__ __launch_bounds__(256, 4)
void gemm_in_hist(const float* __restrict__ X, const ushort* __restrict__ Bfm,
                  const float* __restrict__ bias,
                  const float* __restrict__ gamma, const float* __restrict__ beta,
                  const float* __restrict__ mean, const float* __restrict__ var,
                  ushort* __restrict__ out, uchar* __restrict__ out8,
                  const int* __restrict__ dst, int* __restrict__ cnt,
                  int N, int E, int GB) {
  __shared__ float Cb_all[4 * 16 * 68];
  if (blockIdx.x >= GB) {
    int e = (blockIdx.x - GB) * 256 + threadIdx.x;
    if (e < E) atomicAdd(&cnt[dst[e]], 1);
    return;
  }
  int tid = threadIdx.x, wave = tid >> 6, lane = tid & 63;
  int wm = wave >> 1, wn = wave & 1, quad = lane >> 4, l16 = lane & 15;
  int m0 = blockIdx.x * 64;

  int rowm[2];
  #pragma unroll
  for (int mt = 0; mt < 2; ++mt) {
    int r = m0 + wm * 32 + mt * 16 + l16;
    rowm[mt] = r < N ? r : N - 1;
  }

  float4 f_buf[2][2][2];
  uint4 b_buf[2][4];
  #pragma unroll
  for (int mt = 0; mt < 2; ++mt) {
    const float* p = X + (size_t)rowm[mt] * 256 + quad * 8;
    f_buf[0][mt][0] = *(const float4*)p;
    f_buf[0][mt][1] = *(const float4*)(p + 4);
  }
  {
    const ushort* bp = Bfm + (size_t)(wn * 4 * 256 + lane) * 8;
    #pragma unroll
    for (int nt = 0; nt < 4; ++nt)
      b_buf[0][nt] = *(const uint4*)(bp + nt * 2048);
  }

  f32x4 acc[2][4] = {};

  #pragma unroll
  for (int kt = 0; kt < 8; ++kt) {
    if (kt < 7) {
      int k1 = kt + 1;
      int ko = k1 * 32 + quad * 8;
      #pragma unroll
      for (int mt = 0; mt < 2; ++mt) {
        const float* p = X + (size_t)rowm[mt] * 256 + ko;
        f_buf[k1 & 1][mt][0] = *(const float4*)p;
        f_buf[k1 & 1][mt][1] = *(const float4*)(p + 4);
      }
      const ushort* bp = Bfm + ((size_t)(k1 >> 2) * 16384 +
                                (size_t)((wn * 4) * 256 + (k1 & 3) * 64 + lane) * 8);
      #pragma unroll
      for (int nt = 0; nt < 4; ++nt)
        b_buf[k1 & 1][nt] = *(const uint4*)(bp + nt * 2048);
    }
    __builtin_amdgcn_sched_barrier(0);
    #pragma unroll
    for (int mt = 0; mt < 2; ++mt) {
      float4 lo = f_buf[kt & 1][mt][0], hi = f_buf[kt & 1][mt][1];
      uint4 av;
      av.x = pack2(lo.x, lo.y); av.y = pack2(lo.z, lo.w);
      av.z = pack2(hi.x, hi.y); av.w = pack2(hi.z, hi.w);
      bf16x8 af = __builtin_bit_cast(bf16x8, av);
      #pragma unroll
      for (int nt = 0; nt < 4; ++nt)
        acc[mt][nt] = __builtin_amdgcn_mfma_f32_16x16x32_bf16(
            af, __builtin_bit_cast(bf16x8, b_buf[kt & 1][nt]), acc[mt][nt], 0, 0, 0);
    }
  }

  #pragma unroll
  for (int nt = 0; nt < 4; ++nt) {
    int c = wn * 64 + nt * 16 + l16;
    float sc = gamma[c] * rsqrtf(var[c] + BN_EPS);
    float sh = beta[c] - mean[c] * sc;
    float bi = bias[c];
    #pragma unroll
    for (int mt = 0; mt < 2; ++mt)
      #pragma unroll
      for (int r = 0; r < 4; ++r)
        acc[mt][nt][r] = fmaxf((acc[mt][nt][r] + bi) * sc + sh, 0.f);
  }

  float* Cb = Cb_all + wave * (16 * 68);
  #pragma unroll
  for (int mt = 0; mt < 2; ++mt) {
    #pragma unroll
    for (int nt = 0; nt < 4; ++nt)
      #pragma unroll
      for (int r = 0; r < 4; ++r)
        Cb[(quad * 4 + r) * 68 + nt * 16 + l16] = acc[mt][nt][r];
    #pragma unroll
    for (int i = 0; i < 4; ++i) {
      int idx = i * 64 + lane, rowl = idx >> 4, seg = idx & 15;
      int grow = m0 + wm * 32 + mt * 16 + rowl;
      if (grow < N) {
        float4 vv = *(float4*)&Cb[rowl * 68 + seg * 4];
        uint2 o;
        o.x = pack2(vv.x, vv.y); o.y = pack2(vv.z, vv.w);
        *(uint2*)(out + (size_t)grow * 128 + wn * 64 + seg * 4) = o;
        uint u8 = f2e4m3(vv.x) | (f2e4m3(vv.y) << 8) |
                  (f2e4m3(vv.z) << 16) | (f2e4m3(vv.w) << 24);
        *(uint*)(out8 + (size_t)grow * 128 + wn * 64 + seg * 4) = u8;
      }
    }
  }
}

// ---------------- launch ----------------

extern "C" void kernel_launch(void* const* d_in, const int* in_sizes, int n_in,
                              void* d_out, int out_size, void* d_ws, size_t ws_size,
                              hipStream_t stream) {
  const float* x      = (const float*)d_in[0];
  const int*   eidx   = (const int*)d_in[1];
  const float* W_in   = (const float*)d_in[2];
  const float* b_in   = (const float*)d_in[3];
  const float* bng_in = (const float*)d_in[4];
  const float* bnb_in = (const float*)d_in[5];
  const float* bnm_in = (const float*)d_in[6];
  const float* bnv_in = (const float*)d_in[7];
  const float* Wl     = (const float*)d_in[8];
  const float* bl     = (const float*)d_in[9];
  const float* Wr     = (const float*)d_in[10];
  const float* bng    = (const float*)d_in[11];
  const float* bnb    = (const float*)d_in[12];
  const float* bnm    = (const float*)d_in[13];
  const float* bnv    = (const float*)d_in[14];

  const int N = in_sizes[0] / 256;
  const int E = in_sizes[1] / 2;
  const int NB = (N + 255) / 256;
  const int* src = eidx;
  const int* dst = eidx + E;

  char* ws = (char*)d_ws;
  size_t off = 0;
  auto alloc = [&](size_t bytes) {
    void* p = ws + off;
    off = (off + bytes + 255) & ~(size_t)255;
    return p;
  };
  // Total footprint ~68 MB (round-11-proven; rounds 9/10 at 94-106 MB died).
  int* zreg     = (int*)alloc((size_t)(2 * N + 1) * 4);   // cnt(deg) | cur | cursor
  int* cnt      = zreg;
  int* cur      = zreg + N;
  int* cursor   = zreg + 2 * N;
  int* rowbeg   = (int*)alloc((size_t)N * 4);
  int* col      = (int*)alloc((size_t)E * 4);
  ushort* Bfm   = (ushort*)alloc(4 * 32768 * 2);   // split-K frag-major: [in, l0, l1, l2]
  ushort* bufA  = (ushort*)alloc((size_t)N * 128 * 2);
  ushort* bufB  = (ushort*)alloc((size_t)N * 128 * 2);
  uchar* h8     = (uchar*)alloc((size_t)N * 128);   // fp8 e4m3 shadow (agg path)
  (void)ws_size; (void)n_in; (void)out_size;

  const int EB = (E + 255) / 256;
  const int GB = (N + 63) / 64;
  const int NZ = 2 * N + 1;
  const int NB2 = (NZ + 255) / 256;

  // zero counters + weight prep in ONE kernel (completes before gemm_in_hist)
  zero_prep_kernel<<<NB2 + 64, 256, 0, stream>>>(zreg, NZ, W_in, Wl, Wr, Bfm, NB2);

  // input projection UNION edge histogram (independent outputs)
  gemm_in_hist<<<GB + EB, 256, 0, stream>>>(x, Bfm, b_in, bng_in, bnb_in, bnm_in, bnv_in,
                                            bufA, h8, dst, cnt, N, E, GB);

  // CSR range reserve (bump allocation), then fill
  reserve_kernel<<<NB, 256, 0, stream>>>(cnt, rowbeg, cursor, N);
  fill_kernel<<<EB, 256, 0, stream>>>(src, dst, rowbeg, cur, col, E);

  // 3 SAGE layers, 2-buffer rotation with in-place GEMM over the agg buffer
  for (int l = 0; l < 3; ++l) {
    ushort* h_in   = (l & 1) ? bufB : bufA;
    ushort* aggbuf = (l & 1) ? bufA : bufB;
    agg_kernel<<<(N + 15) / 16, 256, 0, stream>>>(rowbeg, cnt, col, h8, aggbuf, N);
    const ushort* BfmL = Bfm + (size_t)(l + 1) * 32768;
    const float* biasL = bl + l * 128;
    if (l < 2) {
      gemm_layer<false><<<GB, 256, 0, stream>>>(aggbuf, h_in, BfmL, biasL,
          bng + l * 128, bnb + l * 128, bnm + l * 128, bnv + l * 128,
          h_in, (void*)aggbuf, h8, N);
    } else {
      gemm_layer<true><<<GB, 256, 0, stream>>>(aggbuf, h_in, BfmL, biasL,
          bng + l * 128, bnb + l * 128, bnm + l * 128, bnv + l * 128,
          h_in, d_out, nullptr, N);
    }
  }
}